// Round 5
// baseline (686.754 us; speedup 1.0000x reference)
//
#include <hip/hip_runtime.h>
#include <stdint.h>

#define BB 4
#define TT 2048
#define CC 1024
#define HH 16

typedef __bf16 bf16x8 __attribute__((ext_vector_type(8)));
typedef float f32x4 __attribute__((ext_vector_type(4)));
typedef float f32x16 __attribute__((ext_vector_type(16)));
typedef unsigned short ushort8 __attribute__((ext_vector_type(8)));
typedef unsigned short ushort4v __attribute__((ext_vector_type(4)));

__device__ __forceinline__ unsigned short f2b(float f) {
    union { float f; unsigned u; } v; v.f = f;
    unsigned r = v.u + 0x7FFFu + ((v.u >> 16) & 1u);   // RNE
    return (unsigned short)(r >> 16);
}
// pack two positive floats to bf16x2 (round-half-up) in one v_perm each
__device__ __forceinline__ unsigned pack2(float a, float b) {
    union { float f; unsigned u; } ua, ub; ua.f = a; ub.f = b;
    return __builtin_amdgcn_perm(ub.u + 0x8000u, ua.u + 0x8000u, 0x07060302u);
}
__device__ __forceinline__ float fexp2(float x) {
#if __has_builtin(__builtin_amdgcn_exp2f)
    return __builtin_amdgcn_exp2f(x);
#else
    return exp2f(x);
#endif
}
#define LOG2E 1.4426950408889634f

// async global->LDS, 16B per lane
#define ASYNC16(gp, lp) __builtin_amdgcn_global_load_lds( \
    (const __attribute__((address_space(1))) void*)(gp),  \
    (__attribute__((address_space(3))) void*)(lp), 16, 0, 0)

// ---------------- fp32 -> bf16 cast ----------------
__global__ __launch_bounds__(256) void k_cast(const float* __restrict__ in,
                                              unsigned short* __restrict__ out, int n) {
    int i = (blockIdx.x * 256 + threadIdx.x) * 4;
    if (i >= n) return;
    float4 v = *(const float4*)(in + i);
    ushort4v o;
    o.x = f2b(v.x); o.y = f2b(v.y); o.z = f2b(v.z); o.w = f2b(v.w);
    *(ushort4v*)(out + i) = o;
}

// ------------- transpose + cast: fp32 [R][Cc] -> bf16 [Cc][R] -------------
__global__ __launch_bounds__(256) void k_transpose_bf16(const float* __restrict__ in,
                                                        unsigned short* __restrict__ out,
                                                        int R, int Cc) {
    __shared__ float tile[32][33];
    int bx = blockIdx.x * 32, by = blockIdx.y * 32;
    int tx = threadIdx.x, ty = threadIdx.y;   // (32, 8)
    for (int i = 0; i < 32; i += 8)
        tile[ty + i][tx] = in[(size_t)(by + ty + i) * Cc + bx + tx];
    __syncthreads();
    for (int i = 0; i < 32; i += 8)
        out[(size_t)(bx + ty + i) * R + by + tx] = f2b(tile[tx][ty + i]);
}

// ------------- bf16 MFMA GEMM: 128x128 tile, BK=32, async staging (m97 structure) -------------
// LDS-staged coalesced epilogue (As/Bs dead after K-loop; reuse as 17 KB scratch).
#define QSCALE 0.125f
template <int MODE>
__global__ __launch_bounds__(256) void k_gemm(const unsigned short* __restrict__ A,
                                              const unsigned short* __restrict__ Bt,
                                              const float* __restrict__ bias,
                                              float* __restrict__ outf,
                                              unsigned short* __restrict__ qo,
                                              unsigned short* __restrict__ ko,
                                              unsigned short* __restrict__ vo,
                                              int M, int N, int K) {
    __shared__ unsigned short sm[8704];   // As(4096) + Bs(4096); epilogue scratch (64x136 u16 / 32x132 f32)
    unsigned short* As = sm;
    unsigned short* Bs = sm + 4096;
    const int t = threadIdx.x;
    const int lane = t & 63;
    const int c = lane & 15, qd = lane >> 4;
    const int wave = t >> 6;
    const int wr = (wave >> 1) * 64, wc = (wave & 1) * 64;
    const int bm = blockIdx.x * 128, bn = blockIdx.y * 128;

    f32x4 acc[4][4] = {};

    const unsigned short* Ap = A + (size_t)(bm + (t >> 2)) * K + (t & 3) * 8;
    const unsigned short* Bp = Bt + (size_t)(bn + (t >> 2)) * K + (t & 3) * 8;
    unsigned short* Asw = &As[t * 8];
    unsigned short* Bsw = &Bs[t * 8];

    for (int k0 = 0; k0 < K; k0 += 32) {
        __syncthreads();
        ASYNC16(Ap + k0, Asw);
        ASYNC16(Ap + (size_t)64 * K + k0, Asw + 2048);
        ASYNC16(Bp + k0, Bsw);
        ASYNC16(Bp + (size_t)64 * K + k0, Bsw + 2048);
        __syncthreads();
        bf16x8 af[4], bfr[4];
        for (int i = 0; i < 4; i++)
            af[i] = *(const bf16x8*)&As[(wr + i * 16 + c) * 32 + qd * 8];
        for (int j = 0; j < 4; j++)
            bfr[j] = *(const bf16x8*)&Bs[(wc + j * 16 + c) * 32 + qd * 8];
        for (int i = 0; i < 4; i++)
            for (int j = 0; j < 4; j++)
                acc[i][j] = __builtin_amdgcn_mfma_f32_16x16x32_bf16(af[i], bfr[j], acc[i][j], 0, 0, 0);
    }

    // add bias in-register (C/D layout: col=lane&15, row=qd*4+reg  [m89/m91])
    for (int j = 0; j < 4; j++) {
        float bv = bias[bn + wc + j * 16 + c];
        for (int i = 0; i < 4; i++)
            for (int r = 0; r < 4; r++)
                acc[i][j][r] += bv;
    }

    if (MODE == 0) {
        // fp32 out: 4 passes (i=p), 32 rows x 128 cols staged, stride 132 f32 (16B-aligned rows)
        float* smf = (float*)sm;
        for (int p = 0; p < 4; p++) {
            __syncthreads();
            int lr0 = (wr >> 2) + qd * 4;      // wr=0 -> 0..15 band, wr=64 -> 16..31 band
            for (int j = 0; j < 4; j++) {
                int col = wc + j * 16 + c;
                for (int r = 0; r < 4; r++)
                    smf[(lr0 + r) * 132 + col] = acc[p][j][r];
            }
            __syncthreads();
            for (int op = 0; op < 4; op++) {
                int lr = (t >> 5) + op * 8;
                int ch = (t & 31) * 4;
                float4 v = *(float4*)&smf[lr * 132 + ch];
                int grow = bm + (lr >> 4) * 64 + 16 * p + (lr & 15);
                *(float4*)&outf[(size_t)grow * N + bn + ch] = v;
            }
        }
    } else if (bn < 2048) {
        // Q/K out (bf16): 2 passes (i in {2p,2p+1}), 64 rows x 128 cols, stride 136 u16
        unsigned short* dst = (bn < 1024) ? qo : ko;
        const int dcol0 = (bn < 1024) ? bn : bn - 1024;
        const float sc = (bn < 1024) ? QSCALE : 1.0f;
        for (int p = 0; p < 2; p++) {
            __syncthreads();
            for (int ii = 0; ii < 2; ii++) {
                int i = 2 * p + ii;
                int lr0 = (wr >> 1) + ii * 16 + qd * 4;   // (wr>>6)*32 = wr>>1
                for (int j = 0; j < 4; j++) {
                    int col = wc + j * 16 + c;
                    for (int r = 0; r < 4; r++)
                        sm[(lr0 + r) * 136 + col] = f2b(acc[i][j][r] * sc);
                }
            }
            __syncthreads();
            for (int op = 0; op < 4; op++) {
                int lr = (t >> 4) + op * 16;
                int ch = (t & 15) * 8;
                ushort8 v = *(ushort8*)&sm[lr * 136 + ch];
                int grow = bm + (lr >> 5) * 64 + 32 * p + (lr & 31);
                *(ushort8*)&dst[(size_t)grow * 1024 + dcol0 + ch] = v;
            }
        }
    } else {
        // V out -> vT16[b*1024 + d][t]: 2 passes (j in {2p,2p+1}), 64 d-rows x 128 t, stride 136
        const int bseg = bm >> 11;
        const int bmt = bm & 2047;
        for (int p = 0; p < 2; p++) {
            __syncthreads();
            for (int jj = 0; jj < 2; jj++) {
                int j = 2 * p + jj;
                int dl = (wc >> 1) + jj * 16 + c;         // (wc>>6)*32 = wc>>1
                for (int i = 0; i < 4; i++) {
                    int tl = wr + i * 16 + qd * 4;
                    ushort4v pk;
                    pk.x = f2b(acc[i][j][0]); pk.y = f2b(acc[i][j][1]);
                    pk.z = f2b(acc[i][j][2]); pk.w = f2b(acc[i][j][3]);
                    *(ushort4v*)&sm[dl * 136 + tl] = pk;
                }
            }
            __syncthreads();
            for (int op = 0; op < 4; op++) {
                int dl = (t >> 4) + op * 16;
                int ch = (t & 15) * 8;
                ushort8 v = *(ushort8*)&sm[dl * 136 + ch];
                int d = (bn - 2048) + (dl >> 5) * 64 + 32 * p + (dl & 31);
                *(ushort8*)&vo[((size_t)bseg * 1024 + d) * 2048 + bmt + ch] = v;
            }
        }
    }
}

// ------------- flash attention, S^T form, 32x32x16 MFMA -------------
// LDS: q region (18 KB) overlaps k/vt (q dead after qf extraction) -> 8 blocks/CU.
// 32x32x16 frags: A[m=lane&31][k=(lane>>5)*8+e], B[k=(lane>>5)*8+e][n=lane&31],
// C/D: col=lane&31, row=(reg&3)+8*(reg>>2)+4*(lane>>5)  [m74/m101]
__global__ __launch_bounds__(256, 8) void k_attn(const unsigned short* __restrict__ q16,
                                                 const unsigned short* __restrict__ k16,
                                                 const unsigned short* __restrict__ vT16,
                                                 unsigned short* __restrict__ y16) {
    const int h = blockIdx.y, b = blockIdx.z;
    // balance swizzle: stride-256 co-resident blocks share (x,h), alternate b-parity;
    // XOR pairs qi with 15-qi so each quadruple sums to a constant 68 tiles.
    const int qi = (((int)blockIdx.x + h) & 15) ^ ((b & 1) ? 15 : 0);
    __shared__ unsigned short smem[128 * 72];          // q_s [128][72]; then k_s/vt_s overlap
    unsigned short* q_s = smem;
    unsigned short* k_s = smem;                        // [64][72]
    unsigned short* vt_s = smem + 64 * 72;             // [64][72]
    const int t = threadIdx.x, lane = t & 63, wave = t >> 6;
    const int l31 = lane & 31, hl = lane >> 5;
    const int wq = wave * 32;

    // stage Q tile 128x64 (already scaled)
    {
        int row = t >> 1, c32 = (t & 1) * 32;
        const unsigned short* src = q16 + ((size_t)(b * TT + qi * 128 + row)) * CC + h * 64 + c32;
        ushort8 v0 = *(const ushort8*)(src);
        ushort8 v1 = *(const ushort8*)(src + 8);
        ushort8 v2 = *(const ushort8*)(src + 16);
        ushort8 v3 = *(const ushort8*)(src + 24);
        *(ushort8*)&q_s[row * 72 + c32] = v0;
        *(ushort8*)&q_s[row * 72 + c32 + 8] = v1;
        *(ushort8*)&q_s[row * 72 + c32 + 16] = v2;
        *(ushort8*)&q_s[row * 72 + c32 + 24] = v3;
    }
    __syncthreads();
    bf16x8 qf[4];
    for (int s = 0; s < 4; s++)
        qf[s] = *(const bf16x8*)&q_s[(wq + l31) * 72 + s * 16 + hl * 8];
    // q_s dead from here; k_s/vt_s overwrite after the loop's first barrier.

    f32x16 oacc[2] = {};
    float m = -3e38f, l = 0.f;
    const int qmaxw = qi * 128 + wq + 31;
    const int qminw = qi * 128 + wq;
    const int qg = qi * 128 + wq + l31;
    const int jn = 2 * qi + 2;
    const unsigned short* kbase = k16 + (size_t)b * TT * CC + h * 64;
    const unsigned short* vbase = vT16 + (((size_t)b * 16 + h) * 64) * TT;

    const int row = t >> 2, c16 = (t & 3) * 16;
    const unsigned short* ksrc = kbase + (size_t)row * CC + c16;
    const unsigned short* vsrc = vbase + (size_t)row * TT + c16;
    ushort8 ka = *(const ushort8*)ksrc, kb = *(const ushort8*)(ksrc + 8);
    ushort8 va = *(const ushort8*)vsrc, vb = *(const ushort8*)(vsrc + 8);

    for (int j = 0; j < jn; j++) {
        __syncthreads();   // all waves done reading prev k_s/vt_s (and q_s on first iter)
        *(ushort8*)&k_s[row * 72 + c16] = ka;
        *(ushort8*)&k_s[row * 72 + c16 + 8] = kb;
        *(ushort8*)&vt_s[row * 72 + c16] = va;
        *(ushort8*)&vt_s[row * 72 + c16 + 8] = vb;
        __syncthreads();
        if (j + 1 < jn) {   // prefetch next tile; latency hides behind compute
            const unsigned short* kn = ksrc + (size_t)(j + 1) * 64 * CC;
            const unsigned short* vn = vsrc + (j + 1) * 64;
            ka = *(const ushort8*)kn; kb = *(const ushort8*)(kn + 8);
            va = *(const ushort8*)vn; vb = *(const ushort8*)(vn + 8);
        }
        if (j * 64 > qmaxw) continue;   // fully-masked for this wave (wave-uniform)

        // S^T = K * Q^T
        f32x16 sacc[2] = {};
        for (int c2 = 0; c2 < 2; c2++)
            for (int s = 0; s < 4; s++) {
                bf16x8 kf = *(const bf16x8*)&k_s[(c2 * 32 + l31) * 72 + s * 16 + hl * 8];
                sacc[c2] = __builtin_amdgcn_mfma_f32_32x32x16_bf16(kf, qf[s], sacc[c2], 0, 0, 0);
            }

        if (j * 64 + 63 > qminw) {   // diagonal tile: mask kv > q
            for (int c2 = 0; c2 < 2; c2++)
                for (int r = 0; r < 16; r++) {
                    int kvg = j * 64 + c2 * 32 + (r & 3) + 8 * (r >> 2) + 4 * hl;
                    if (kvg > qg) sacc[c2][r] = -1e30f;
                }
        }

        // online softmax in exp2 domain
        float mx = -1e30f;
        for (int c2 = 0; c2 < 2; c2++)
            for (int r = 0; r < 16; r++) mx = fmaxf(mx, sacc[c2][r]);
        mx = fmaxf(mx, __shfl_xor(mx, 32, 64));
        float mn = fmaxf(m, mx);
        float negmnl = -mn * LOG2E;
        float alpha = fexp2(fmaf(m, LOG2E, negmnl));
        m = mn;
        float sum = 0.f;
        unsigned pg[2][4][2];
        for (int c2 = 0; c2 < 2; c2++)
            for (int g = 0; g < 4; g++) {
                float p0 = fexp2(fmaf(sacc[c2][g * 4 + 0], LOG2E, negmnl));
                float p1 = fexp2(fmaf(sacc[c2][g * 4 + 1], LOG2E, negmnl));
                float p2 = fexp2(fmaf(sacc[c2][g * 4 + 2], LOG2E, negmnl));
                float p3 = fexp2(fmaf(sacc[c2][g * 4 + 3], LOG2E, negmnl));
                sum += (p0 + p1) + (p2 + p3);
                pg[c2][g][0] = pack2(p0, p1);
                pg[c2][g][1] = pack2(p2, p3);
            }
        sum += __shfl_xor(sum, 32, 64);
        l = l * alpha + sum;
        if (__ballot(alpha != 1.0f)) {   // skip rescale once max has stabilized
            for (int c2 = 0; c2 < 2; c2++)
                for (int r = 0; r < 16; r++) oacc[c2][r] *= alpha;
        }

        // C-layout -> B-operand layout: half-swap with partner lane (lane^32)
        bf16x8 pf[4];
        for (int c2 = 0; c2 < 2; c2++)
            for (int pr = 0; pr < 2; pr++) {
                unsigned se0 = hl ? pg[c2][2 * pr][0] : pg[c2][2 * pr + 1][0];
                unsigned se1 = hl ? pg[c2][2 * pr][1] : pg[c2][2 * pr + 1][1];
                unsigned r0 = (unsigned)__shfl_xor((int)se0, 32, 64);
                unsigned r1 = (unsigned)__shfl_xor((int)se1, 32, 64);
                union { unsigned u[4]; bf16x8 v; } fr;
                fr.u[0] = hl ? r0 : pg[c2][2 * pr][0];
                fr.u[1] = hl ? r1 : pg[c2][2 * pr][1];
                fr.u[2] = hl ? pg[c2][2 * pr + 1][0] : r0;
                fr.u[3] = hl ? pg[c2][2 * pr + 1][1] : r1;
                pf[c2 * 2 + pr] = fr.v;
            }

        // O^T += V^T * P^T
        for (int s = 0; s < 4; s++)
            for (int c2o = 0; c2o < 2; c2o++) {
                bf16x8 vf = *(const bf16x8*)&vt_s[(c2o * 32 + l31) * 72 + s * 16 + hl * 8];
                oacc[c2o] = __builtin_amdgcn_mfma_f32_32x32x16_bf16(vf, pf[s], oacc[c2o], 0, 0, 0);
            }
    }

    // epilogue: y[token=qg][h*64 + d]
    float rl = 1.0f / l;
    size_t rowb = ((size_t)b * TT + qg) * CC + h * 64;
    for (int c2 = 0; c2 < 2; c2++)
        for (int g = 0; g < 4; g++) {
            ushort4v pk;
            pk.x = f2b(oacc[c2][g * 4 + 0] * rl);
            pk.y = f2b(oacc[c2][g * 4 + 1] * rl);
            pk.z = f2b(oacc[c2][g * 4 + 2] * rl);
            pk.w = f2b(oacc[c2][g * 4 + 3] * rl);
            *(ushort4v*)&y16[rowb + c2 * 32 + g * 8 + hl * 4] = pk;
        }
}

extern "C" void kernel_launch(void* const* d_in, const int* in_sizes, int n_in,
                              void* d_out, int out_size, void* d_ws, size_t ws_size,
                              hipStream_t stream) {
    const float* x     = (const float*)d_in[0];
    const float* Wqkv  = (const float*)d_in[1];
    const float* bqkv  = (const float*)d_in[2];
    const float* Wproj = (const float*)d_in[3];
    const float* bproj = (const float*)d_in[4];
    float* out = (float*)d_out;

    const int M = BB * TT;   // 8192
    unsigned short* x16    = (unsigned short*)d_ws;          // M*C
    unsigned short* y16    = x16;                            // alias (x dead after GEMM1)
    unsigned short* wqkvT  = x16 + (size_t)M * CC;           // 3C*C
    unsigned short* wprojT = wqkvT + (size_t)3 * CC * CC;    // C*C
    unsigned short* q16    = wprojT + (size_t)CC * CC;       // M*C (scaled)
    unsigned short* k16    = q16 + (size_t)M * CC;           // M*C
    unsigned short* vT16   = k16 + (size_t)M * CC;           // [B*H][64][T] = M*C

    k_cast<<<(M * CC) / 1024, 256, 0, stream>>>(x, x16, M * CC);
    k_transpose_bf16<<<dim3(3 * CC / 32, CC / 32), dim3(32, 8), 0, stream>>>(Wqkv, wqkvT, CC, 3 * CC);
    k_transpose_bf16<<<dim3(CC / 32, CC / 32), dim3(32, 8), 0, stream>>>(Wproj, wprojT, CC, CC);
    k_gemm<1><<<dim3(M / 128, 3 * CC / 128), 256, 0, stream>>>(x16, wqkvT, bqkv, nullptr,
                                                               q16, k16, vT16, M, 3 * CC, CC);
    k_attn<<<dim3(TT / 128, HH, BB), 256, 0, stream>>>(q16, k16, vT16, y16);
    k_gemm<0><<<dim3(M / 128, CC / 128), 256, 0, stream>>>(y16, wprojT, bproj, out,
                                                           nullptr, nullptr, nullptr, M, CC, CC);
}

// Round 6
// 257.302 us; speedup vs baseline: 2.6691x; 2.6691x over previous
//
#include <hip/hip_runtime.h>
#include <stdint.h>

#define BB 4
#define TT 2048
#define CC 1024
#define HH 16

typedef __bf16 bf16x8 __attribute__((ext_vector_type(8)));
typedef float f32x4 __attribute__((ext_vector_type(4)));
typedef float f32x16 __attribute__((ext_vector_type(16)));
typedef unsigned short ushort8 __attribute__((ext_vector_type(8)));
typedef unsigned short ushort4v __attribute__((ext_vector_type(4)));

__device__ __forceinline__ unsigned short f2b(float f) {
    union { float f; unsigned u; } v; v.f = f;
    unsigned r = v.u + 0x7FFFu + ((v.u >> 16) & 1u);   // RNE
    return (unsigned short)(r >> 16);
}
// pack two positive floats to bf16x2 (round-half-up) in one v_perm each
__device__ __forceinline__ unsigned pack2(float a, float b) {
    union { float f; unsigned u; } ua, ub; ua.f = a; ub.f = b;
    return __builtin_amdgcn_perm(ub.u + 0x8000u, ua.u + 0x8000u, 0x07060302u);
}
__device__ __forceinline__ float fexp2(float x) {
#if __has_builtin(__builtin_amdgcn_exp2f)
    return __builtin_amdgcn_exp2f(x);
#else
    return exp2f(x);
#endif
}
#define LOG2E 1.4426950408889634f

// async global->LDS, 16B per lane
#define ASYNC16(gp, lp) __builtin_amdgcn_global_load_lds( \
    (const __attribute__((address_space(1))) void*)(gp),  \
    (__attribute__((address_space(3))) void*)(lp), 16, 0, 0)

// ---------------- fp32 -> bf16 cast ----------------
__global__ __launch_bounds__(256) void k_cast(const float* __restrict__ in,
                                              unsigned short* __restrict__ out, int n) {
    int i = (blockIdx.x * 256 + threadIdx.x) * 4;
    if (i >= n) return;
    float4 v = *(const float4*)(in + i);
    ushort4v o;
    o.x = f2b(v.x); o.y = f2b(v.y); o.z = f2b(v.z); o.w = f2b(v.w);
    *(ushort4v*)(out + i) = o;
}

// ------------- transpose + cast: fp32 [R][Cc] -> bf16 [Cc][R] -------------
__global__ __launch_bounds__(256) void k_transpose_bf16(const float* __restrict__ in,
                                                        unsigned short* __restrict__ out,
                                                        int R, int Cc) {
    __shared__ float tile[32][33];
    int bx = blockIdx.x * 32, by = blockIdx.y * 32;
    int tx = threadIdx.x, ty = threadIdx.y;   // (32, 8)
    for (int i = 0; i < 32; i += 8)
        tile[ty + i][tx] = in[(size_t)(by + ty + i) * Cc + bx + tx];
    __syncthreads();
    for (int i = 0; i < 32; i += 8)
        out[(size_t)(bx + ty + i) * R + by + tx] = f2b(tile[tx][ty + i]);
}

// ------------- bf16 MFMA GEMM: 128x128 tile, BK=32, async staging (m97 structure) -------------
// LDS-staged coalesced epilogue (As/Bs dead after K-loop; reuse as 17 KB scratch).
#define QSCALE 0.125f
template <int MODE>
__global__ __launch_bounds__(256) void k_gemm(const unsigned short* __restrict__ A,
                                              const unsigned short* __restrict__ Bt,
                                              const float* __restrict__ bias,
                                              float* __restrict__ outf,
                                              unsigned short* __restrict__ qo,
                                              unsigned short* __restrict__ ko,
                                              unsigned short* __restrict__ vo,
                                              int M, int N, int K) {
    __shared__ unsigned short sm[8704];   // As(4096) + Bs(4096); epilogue scratch (64x136 u16 / 32x132 f32)
    unsigned short* As = sm;
    unsigned short* Bs = sm + 4096;
    const int t = threadIdx.x;
    const int lane = t & 63;
    const int c = lane & 15, qd = lane >> 4;
    const int wave = t >> 6;
    const int wr = (wave >> 1) * 64, wc = (wave & 1) * 64;
    const int bm = blockIdx.x * 128, bn = blockIdx.y * 128;

    f32x4 acc[4][4] = {};

    const unsigned short* Ap = A + (size_t)(bm + (t >> 2)) * K + (t & 3) * 8;
    const unsigned short* Bp = Bt + (size_t)(bn + (t >> 2)) * K + (t & 3) * 8;
    unsigned short* Asw = &As[t * 8];
    unsigned short* Bsw = &Bs[t * 8];

    for (int k0 = 0; k0 < K; k0 += 32) {
        __syncthreads();
        ASYNC16(Ap + k0, Asw);
        ASYNC16(Ap + (size_t)64 * K + k0, Asw + 2048);
        ASYNC16(Bp + k0, Bsw);
        ASYNC16(Bp + (size_t)64 * K + k0, Bsw + 2048);
        __syncthreads();
        bf16x8 af[4], bfr[4];
        for (int i = 0; i < 4; i++)
            af[i] = *(const bf16x8*)&As[(wr + i * 16 + c) * 32 + qd * 8];
        for (int j = 0; j < 4; j++)
            bfr[j] = *(const bf16x8*)&Bs[(wc + j * 16 + c) * 32 + qd * 8];
        for (int i = 0; i < 4; i++)
            for (int j = 0; j < 4; j++)
                acc[i][j] = __builtin_amdgcn_mfma_f32_16x16x32_bf16(af[i], bfr[j], acc[i][j], 0, 0, 0);
    }

    // add bias in-register (C/D layout: col=lane&15, row=qd*4+reg  [m89/m91])
    for (int j = 0; j < 4; j++) {
        float bv = bias[bn + wc + j * 16 + c];
        for (int i = 0; i < 4; i++)
            for (int r = 0; r < 4; r++)
                acc[i][j][r] += bv;
    }

    if (MODE == 0) {
        // fp32 out: 4 passes (i=p), 32 rows x 128 cols staged, stride 132 f32 (16B-aligned rows)
        float* smf = (float*)sm;
        for (int p = 0; p < 4; p++) {
            __syncthreads();
            int lr0 = (wr >> 2) + qd * 4;      // wr=0 -> 0..15 band, wr=64 -> 16..31 band
            for (int j = 0; j < 4; j++) {
                int col = wc + j * 16 + c;
                for (int r = 0; r < 4; r++)
                    smf[(lr0 + r) * 132 + col] = acc[p][j][r];
            }
            __syncthreads();
            for (int op = 0; op < 4; op++) {
                int lr = (t >> 5) + op * 8;
                int ch = (t & 31) * 4;
                float4 v = *(float4*)&smf[lr * 132 + ch];
                int grow = bm + (lr >> 4) * 64 + 16 * p + (lr & 15);
                *(float4*)&outf[(size_t)grow * N + bn + ch] = v;
            }
        }
    } else if (bn < 2048) {
        // Q/K out (bf16): 2 passes (i in {2p,2p+1}), 64 rows x 128 cols, stride 136 u16
        unsigned short* dst = (bn < 1024) ? qo : ko;
        const int dcol0 = (bn < 1024) ? bn : bn - 1024;
        const float sc = (bn < 1024) ? QSCALE : 1.0f;
        for (int p = 0; p < 2; p++) {
            __syncthreads();
            for (int ii = 0; ii < 2; ii++) {
                int i = 2 * p + ii;
                int lr0 = (wr >> 1) + ii * 16 + qd * 4;   // (wr>>6)*32 = wr>>1
                for (int j = 0; j < 4; j++) {
                    int col = wc + j * 16 + c;
                    for (int r = 0; r < 4; r++)
                        sm[(lr0 + r) * 136 + col] = f2b(acc[i][j][r] * sc);
                }
            }
            __syncthreads();
            for (int op = 0; op < 4; op++) {
                int lr = (t >> 4) + op * 16;
                int ch = (t & 15) * 8;
                ushort8 v = *(ushort8*)&sm[lr * 136 + ch];
                int grow = bm + (lr >> 5) * 64 + 32 * p + (lr & 31);
                *(ushort8*)&dst[(size_t)grow * 1024 + dcol0 + ch] = v;
            }
        }
    } else {
        // V out -> vT16[b*1024 + d][t]: 2 passes (j in {2p,2p+1}), 64 d-rows x 128 t, stride 136
        const int bseg = bm >> 11;
        const int bmt = bm & 2047;
        for (int p = 0; p < 2; p++) {
            __syncthreads();
            for (int jj = 0; jj < 2; jj++) {
                int j = 2 * p + jj;
                int dl = (wc >> 1) + jj * 16 + c;         // (wc>>6)*32 = wc>>1
                for (int i = 0; i < 4; i++) {
                    int tl = wr + i * 16 + qd * 4;
                    ushort4v pk;
                    pk.x = f2b(acc[i][j][0]); pk.y = f2b(acc[i][j][1]);
                    pk.z = f2b(acc[i][j][2]); pk.w = f2b(acc[i][j][3]);
                    *(ushort4v*)&sm[dl * 136 + tl] = pk;
                }
            }
            __syncthreads();
            for (int op = 0; op < 4; op++) {
                int dl = (t >> 4) + op * 16;
                int ch = (t & 15) * 8;
                ushort8 v = *(ushort8*)&sm[dl * 136 + ch];
                int d = (bn - 2048) + (dl >> 5) * 64 + 32 * p + (dl & 31);
                *(ushort8*)&vo[((size_t)bseg * 1024 + d) * 2048 + bmt + ch] = v;
            }
        }
    }
}

// ------------- flash attention, S^T form, 32x32x16 MFMA -------------
// LDS: q region overlaps k/vt (q dead after qf extraction) -> 18 KB.
// __launch_bounds__(256,4): kernel needs ~100 regs/wave; (256,8) caps the unified
// VGPR/AGPR budget at 64 and spills catastrophically (R5: 1.5 GB scratch WRITE_SIZE).
// VGPR-occupancy-capped at 4 waves/EU — structural for this register footprint.
// 32x32x16 frags: A[m=lane&31][k=(lane>>5)*8+e], B[k=(lane>>5)*8+e][n=lane&31],
// C/D: col=lane&31, row=(reg&3)+8*(reg>>2)+4*(lane>>5)  [m74/m101]
__global__ __launch_bounds__(256, 4) void k_attn(const unsigned short* __restrict__ q16,
                                                 const unsigned short* __restrict__ k16,
                                                 const unsigned short* __restrict__ vT16,
                                                 unsigned short* __restrict__ y16) {
    const int h = blockIdx.y, b = blockIdx.z;
    // balance swizzle: stride-256 co-resident blocks share (x,h), alternate b-parity;
    // XOR pairs qi with 15-qi so each quadruple sums to a constant 68 tiles.
    const int qi = (((int)blockIdx.x + h) & 15) ^ ((b & 1) ? 15 : 0);
    __shared__ unsigned short smem[128 * 72];          // q_s [128][72]; then k_s/vt_s overlap
    unsigned short* q_s = smem;
    unsigned short* k_s = smem;                        // [64][72]
    unsigned short* vt_s = smem + 64 * 72;             // [64][72]
    const int t = threadIdx.x, lane = t & 63, wave = t >> 6;
    const int l31 = lane & 31, hl = lane >> 5;
    const int wq = wave * 32;

    // stage Q tile 128x64 (already scaled)
    {
        int row = t >> 1, c32 = (t & 1) * 32;
        const unsigned short* src = q16 + ((size_t)(b * TT + qi * 128 + row)) * CC + h * 64 + c32;
        ushort8 v0 = *(const ushort8*)(src);
        ushort8 v1 = *(const ushort8*)(src + 8);
        ushort8 v2 = *(const ushort8*)(src + 16);
        ushort8 v3 = *(const ushort8*)(src + 24);
        *(ushort8*)&q_s[row * 72 + c32] = v0;
        *(ushort8*)&q_s[row * 72 + c32 + 8] = v1;
        *(ushort8*)&q_s[row * 72 + c32 + 16] = v2;
        *(ushort8*)&q_s[row * 72 + c32 + 24] = v3;
    }
    __syncthreads();
    bf16x8 qf[4];
    for (int s = 0; s < 4; s++)
        qf[s] = *(const bf16x8*)&q_s[(wq + l31) * 72 + s * 16 + hl * 8];
    // q_s dead from here; k_s/vt_s overwrite after the loop's first barrier.

    f32x16 oacc[2] = {};
    float m = -3e38f, l = 0.f;
    const int qmaxw = qi * 128 + wq + 31;
    const int qminw = qi * 128 + wq;
    const int qg = qi * 128 + wq + l31;
    const int jn = 2 * qi + 2;
    const unsigned short* kbase = k16 + (size_t)b * TT * CC + h * 64;
    const unsigned short* vbase = vT16 + (((size_t)b * 16 + h) * 64) * TT;

    const int row = t >> 2, c16 = (t & 3) * 16;
    const unsigned short* ksrc = kbase + (size_t)row * CC + c16;
    const unsigned short* vsrc = vbase + (size_t)row * TT + c16;
    ushort8 ka = *(const ushort8*)ksrc, kb = *(const ushort8*)(ksrc + 8);
    ushort8 va = *(const ushort8*)vsrc, vb = *(const ushort8*)(vsrc + 8);

    for (int j = 0; j < jn; j++) {
        __syncthreads();   // all waves done reading prev k_s/vt_s (and q_s on first iter)
        *(ushort8*)&k_s[row * 72 + c16] = ka;
        *(ushort8*)&k_s[row * 72 + c16 + 8] = kb;
        *(ushort8*)&vt_s[row * 72 + c16] = va;
        *(ushort8*)&vt_s[row * 72 + c16 + 8] = vb;
        __syncthreads();
        if (j + 1 < jn) {   // prefetch next tile; latency hides behind compute
            const unsigned short* kn = ksrc + (size_t)(j + 1) * 64 * CC;
            const unsigned short* vn = vsrc + (j + 1) * 64;
            ka = *(const ushort8*)kn; kb = *(const ushort8*)(kn + 8);
            va = *(const ushort8*)vn; vb = *(const ushort8*)(vn + 8);
        }
        if (j * 64 > qmaxw) continue;   // fully-masked for this wave (wave-uniform)

        // S^T = K * Q^T
        f32x16 sacc[2] = {};
        for (int c2 = 0; c2 < 2; c2++)
            for (int s = 0; s < 4; s++) {
                bf16x8 kf = *(const bf16x8*)&k_s[(c2 * 32 + l31) * 72 + s * 16 + hl * 8];
                sacc[c2] = __builtin_amdgcn_mfma_f32_32x32x16_bf16(kf, qf[s], sacc[c2], 0, 0, 0);
            }

        if (j * 64 + 63 > qminw) {   // diagonal tile: mask kv > q
            for (int c2 = 0; c2 < 2; c2++)
                for (int r = 0; r < 16; r++) {
                    int kvg = j * 64 + c2 * 32 + (r & 3) + 8 * (r >> 2) + 4 * hl;
                    if (kvg > qg) sacc[c2][r] = -1e30f;
                }
        }

        // online softmax in exp2 domain
        float mx = -1e30f;
        for (int c2 = 0; c2 < 2; c2++)
            for (int r = 0; r < 16; r++) mx = fmaxf(mx, sacc[c2][r]);
        mx = fmaxf(mx, __shfl_xor(mx, 32, 64));
        float mn = fmaxf(m, mx);
        float negmnl = -mn * LOG2E;
        float alpha = fexp2(fmaf(m, LOG2E, negmnl));
        m = mn;
        float sum = 0.f;
        unsigned pg[2][4][2];
        for (int c2 = 0; c2 < 2; c2++)
            for (int g = 0; g < 4; g++) {
                float p0 = fexp2(fmaf(sacc[c2][g * 4 + 0], LOG2E, negmnl));
                float p1 = fexp2(fmaf(sacc[c2][g * 4 + 1], LOG2E, negmnl));
                float p2 = fexp2(fmaf(sacc[c2][g * 4 + 2], LOG2E, negmnl));
                float p3 = fexp2(fmaf(sacc[c2][g * 4 + 3], LOG2E, negmnl));
                sum += (p0 + p1) + (p2 + p3);
                pg[c2][g][0] = pack2(p0, p1);
                pg[c2][g][1] = pack2(p2, p3);
            }
        sum += __shfl_xor(sum, 32, 64);
        l = l * alpha + sum;
        if (__ballot(alpha != 1.0f)) {   // skip rescale once max has stabilized
            for (int c2 = 0; c2 < 2; c2++)
                for (int r = 0; r < 16; r++) oacc[c2][r] *= alpha;
        }

        // C-layout -> B-operand layout: half-swap with partner lane (lane^32)
        bf16x8 pf[4];
        for (int c2 = 0; c2 < 2; c2++)
            for (int pr = 0; pr < 2; pr++) {
                unsigned se0 = hl ? pg[c2][2 * pr][0] : pg[c2][2 * pr + 1][0];
                unsigned se1 = hl ? pg[c2][2 * pr][1] : pg[c2][2 * pr + 1][1];
                unsigned r0 = (unsigned)__shfl_xor((int)se0, 32, 64);
                unsigned r1 = (unsigned)__shfl_xor((int)se1, 32, 64);
                union { unsigned u[4]; bf16x8 v; } fr;
                fr.u[0] = hl ? r0 : pg[c2][2 * pr][0];
                fr.u[1] = hl ? r1 : pg[c2][2 * pr][1];
                fr.u[2] = hl ? pg[c2][2 * pr + 1][0] : r0;
                fr.u[3] = hl ? pg[c2][2 * pr + 1][1] : r1;
                pf[c2 * 2 + pr] = fr.v;
            }

        // O^T += V^T * P^T
        for (int s = 0; s < 4; s++)
            for (int c2o = 0; c2o < 2; c2o++) {
                bf16x8 vf = *(const bf16x8*)&vt_s[(c2o * 32 + l31) * 72 + s * 16 + hl * 8];
                oacc[c2o] = __builtin_amdgcn_mfma_f32_32x32x16_bf16(vf, pf[s], oacc[c2o], 0, 0, 0);
            }
    }

    // epilogue: y[token=qg][h*64 + d]
    float rl = 1.0f / l;
    size_t rowb = ((size_t)b * TT + qg) * CC + h * 64;
    for (int c2 = 0; c2 < 2; c2++)
        for (int g = 0; g < 4; g++) {
            ushort4v pk;
            pk.x = f2b(oacc[c2][g * 4 + 0] * rl);
            pk.y = f2b(oacc[c2][g * 4 + 1] * rl);
            pk.z = f2b(oacc[c2][g * 4 + 2] * rl);
            pk.w = f2b(oacc[c2][g * 4 + 3] * rl);
            *(ushort4v*)&y16[rowb + c2 * 32 + g * 8 + hl * 4] = pk;
        }
}

extern "C" void kernel_launch(void* const* d_in, const int* in_sizes, int n_in,
                              void* d_out, int out_size, void* d_ws, size_t ws_size,
                              hipStream_t stream) {
    const float* x     = (const float*)d_in[0];
    const float* Wqkv  = (const float*)d_in[1];
    const float* bqkv  = (const float*)d_in[2];
    const float* Wproj = (const float*)d_in[3];
    const float* bproj = (const float*)d_in[4];
    float* out = (float*)d_out;

    const int M = BB * TT;   // 8192
    unsigned short* x16    = (unsigned short*)d_ws;          // M*C
    unsigned short* y16    = x16;                            // alias (x dead after GEMM1)
    unsigned short* wqkvT  = x16 + (size_t)M * CC;           // 3C*C
    unsigned short* wprojT = wqkvT + (size_t)3 * CC * CC;    // C*C
    unsigned short* q16    = wprojT + (size_t)CC * CC;       // M*C (scaled)
    unsigned short* k16    = q16 + (size_t)M * CC;           // M*C
    unsigned short* vT16   = k16 + (size_t)M * CC;           // [B*H][64][T] = M*C

    k_cast<<<(M * CC) / 1024, 256, 0, stream>>>(x, x16, M * CC);
    k_transpose_bf16<<<dim3(3 * CC / 32, CC / 32), dim3(32, 8), 0, stream>>>(Wqkv, wqkvT, CC, 3 * CC);
    k_transpose_bf16<<<dim3(CC / 32, CC / 32), dim3(32, 8), 0, stream>>>(Wproj, wprojT, CC, CC);
    k_gemm<1><<<dim3(M / 128, 3 * CC / 128), 256, 0, stream>>>(x16, wqkvT, bqkv, nullptr,
                                                               q16, k16, vT16, M, 3 * CC, CC);
    k_attn<<<dim3(TT / 128, HH, BB), 256, 0, stream>>>(q16, k16, vT16, y16);
    k_gemm<0><<<dim3(M / 128, CC / 128), 256, 0, stream>>>(y16, wprojT, bproj, out,
                                                           nullptr, nullptr, nullptr, M, CC, CC);
}